// Round 5
// baseline (87.643 us; speedup 1.0000x reference)
//
#include <hip/hip_runtime.h>

// Problem constants: B=4, T=512, TP=1024, C=32, K=128
#define BB   4
#define TT   512
#define TPN  1024
#define CC   32
#define KK   128
#define EPSF 2.220446049250313e-16f   // np.finfo(float64).eps as f32
#define LOG2E 1.4426950408889634f

#if __has_builtin(__builtin_amdgcn_exp2f)
#define EXP2F(x) __builtin_amdgcn_exp2f(x)
#else
#define EXP2F(x) exp2f(x)
#endif

typedef float f32x2 __attribute__((ext_vector_type(2)));

__device__ __forceinline__ float softplus_f(float x) {
    // stable log(1+exp(x)) = max(x,0) + log1p(exp(-|x|))
    return fmaxf(x, 0.f) + log1pf(__expf(-fabsf(x)));
}

// ---------------------------------------------------------------------------
// Single fused kernel: 2048 blocks x 256 threads (2 tp per block).
//
// Channel-paired layout: lane owns channels (2c, 2c+1), c = tid&15.
//   -> one (pt,ev) LDS load + one (t-pt) sub serve TWO channel-terms
//   -> (a,d) gathers are contiguous b64 in SoA layout
//   -> mul/fma become packed v_pk_*_f32, pushing VALU issue below the
//      trans-pipe (exp) floor: loop becomes exp-rate-bound (~8 cyc/wave-exp).
//
// tid bits: c = tid&15 (channel pair), r = (tid>>4)&7 (8 phases),
// tpl = tid>>7 (2 tp). Phase r handles past indices i = 8j + r (interleaved
// -> per-lane trip counts differ by <=1: near-perfect balance, no masking).
// ---------------------------------------------------------------------------
__global__ __launch_bounds__(256, 8) void GHP_fused(
    const int*   __restrict__ past_event,   // [B,T]
    const float* __restrict__ past_time,    // [B,T] non-decreasing per b
    const float* __restrict__ time_tensor,  // [B,TP]
    const float* __restrict__ mu,           // [C]
    const float* __restrict__ alpha,        // [C,C]
    const float* __restrict__ delta,        // [C,C]
    const float* __restrict__ cf_logits,    // [K]
    const int*   __restrict__ ftc,          // [K]
    float*       __restrict__ out)          // [B,TP,K]
{
    __shared__ __align__(16) f32x2 nd2_s[CC * CC / 2];   // 4 KB: -(sp(delta)+eps)*log2e, pairs
    __shared__ __align__(16) f32x2 a2_s[CC * CC / 2];    // 4 KB: sp(alpha), pairs
    __shared__ __align__(16) float2 ptev_s[8 * 64];      // 4 KB: [phase][j] = (pt, (ev*16) bits)
    __shared__ float e_s[KK];                            // softmax numerators
    __shared__ int   ftc_s[KK];
    __shared__ float den_s[CC];                          // per-coarse softmax denominators
    __shared__ float spmu_s[CC];
    __shared__ __align__(16) f32x2 part2_s[2 * 8 * 16];  // 2 KB phase partials (tp, r, cpair)

    const int tid = threadIdx.x;
    const int b   = blockIdx.x >> 9;            // 512 blocks per batch
    const int tp0 = (blockIdx.x & 511) << 1;

    // ---- Phase 1: staging + per-block prep ----
    // Flat float view of the pair arrays is exactly [e][ch] layout.
    #pragma unroll
    for (int idx = tid; idx < CC * CC; idx += 256) {
        ((float*)a2_s)[idx]  = softplus_f(alpha[idx]);
        ((float*)nd2_s)[idx] = -(softplus_f(delta[idx]) + EPSF) * LOG2E;
    }
    #pragma unroll
    for (int i = tid; i < TT; i += 256) {
        const int r = i & 7, j = i >> 3;
        ptev_s[(r << 6) + j] = make_float2(past_time[b * TT + i],
                                           __int_as_float(past_event[b * TT + i] << 4));
    }
    if (tid < KK) {
        // no max-subtraction needed: logits ~ +-0.5; ratio e/den is invariant
        e_s[tid] = __expf(cf_logits[tid]);
        ftc_s[tid] = ftc[tid];
    }
    if (tid < CC) {
        den_s[tid]  = 0.f;
        spmu_s[tid] = softplus_f(mu[tid]);
    }
    __syncthreads();
    if (tid < KK) atomicAdd(&den_s[ftc_s[tid]], e_s[tid]);   // fenced by sync after main loop

    // ---- Phase 2: main Hawkes accumulation ----
    const int c   = tid & 15;              // channel pair -> channels 2c, 2c+1
    const int r   = (tid >> 4) & 7;        // phase
    const int tpl = tid >> 7;              // tp within block
    const float t = time_tensor[b * TPN + tp0 + tpl];

    // exact per-lane trip count: lower_bound over 64 entries (65 outcomes)
    // -> 7 guarded halvings
    const float2* pp = ptev_s + (r << 6);
    int lo = 0, hi = 64;
    #pragma unroll
    for (int s = 0; s < 7; ++s) {
        const int mid = (lo + hi) >> 1;
        const bool go = (lo < hi) && ((t - pp[mid].x) > EPSF);
        lo = go ? mid + 1 : lo;
        hi = go ? hi : mid;
    }
    const int J = lo;

    f32x2 acc0 = {0.f, 0.f}, acc1 = {0.f, 0.f};
    int j = 0;
    #pragma unroll 2
    for (; j + 2 <= J; j += 2) {
        const float4 q = *(const float4*)(pp + j);       // terms j, j+1
        const int i0 = __float_as_int(q.y) + c;
        const int i1 = __float_as_int(q.w) + c;
        const f32x2 nd0 = nd2_s[i0], aa0 = a2_s[i0];
        const f32x2 nd1 = nd2_s[i1], aa1 = a2_s[i1];
        const float et0 = t - q.x;
        const float et1 = t - q.z;
        const f32x2 g0 = nd0 * et0;                      // v_pk_mul_f32
        const f32x2 g1 = nd1 * et1;
        const f32x2 ex0 = {EXP2F(g0.x), EXP2F(g0.y)};
        const f32x2 ex1 = {EXP2F(g1.x), EXP2F(g1.y)};
        acc0 += aa0 * ex0;                               // v_pk_fma_f32
        acc1 += aa1 * ex1;
    }
    if (j < J) {
        const float2 pe = pp[j];
        const int i0 = __float_as_int(pe.y) + c;
        const f32x2 nd0 = nd2_s[i0], aa0 = a2_s[i0];
        const f32x2 g0 = nd0 * (t - pe.x);
        const f32x2 ex0 = {EXP2F(g0.x), EXP2F(g0.y)};
        acc0 += aa0 * ex0;
    }
    part2_s[((tpl << 3) + r) * 16 + c] = acc0 + acc1;
    __syncthreads();

    // ---- Phase 3: reduce 8 phases, softmax divide, fan-out to K ----
    {
        const int k   = tid & 127;
        const int tpe = tid >> 7;
        const int ck  = ftc_s[k];
        const float* ps = (const float*)(part2_s + (tpe << 7));  // [8][32] floats
        float inten = spmu_s[ck];
        #pragma unroll
        for (int rr = 0; rr < 8; ++rr) inten += ps[rr * CC + ck];
        const float p = e_s[k] / den_s[ck];
        out[(size_t)(b * TPN + tp0 + tpe) * KK + k] = inten * p;
    }
}

extern "C" void kernel_launch(void* const* d_in, const int* in_sizes, int n_in,
                              void* d_out, int out_size, void* d_ws, size_t ws_size,
                              hipStream_t stream) {
    const int*   past_event  = (const int*)  d_in[0];
    const float* past_time   = (const float*)d_in[1];
    const float* time_tensor = (const float*)d_in[2];
    const float* mu          = (const float*)d_in[3];
    const float* alpha       = (const float*)d_in[4];
    const float* delta       = (const float*)d_in[5];
    const float* cf_logits   = (const float*)d_in[6];
    const int*   ftc         = (const int*)  d_in[7];
    float*       out         = (float*)d_out;

    GHP_fused<<<BB * (TPN / 2), 256, 0, stream>>>(past_event, past_time, time_tensor,
                                                  mu, alpha, delta, cf_logits, ftc, out);
}